// Round 10
// baseline (200.276 us; speedup 1.0000x reference)
//
#include <hip/hip_runtime.h>
#include <math.h>

// Problem constants
#define DIM   384
#define NQKV  1152
#define IMG   56
#define ROWS_PER_B (IMG*IMG)           // 3136 pixels per batch image

typedef unsigned short u16;
typedef unsigned int u32;
typedef __attribute__((ext_vector_type(4))) float f32x4;
typedef __attribute__((ext_vector_type(8))) short s16x8;

__device__ __forceinline__ u16 f2b(float f) {           // fp32 -> bf16 RNE
    unsigned u = __float_as_uint(f);
    return (u16)((u + 0x7fffu + ((u >> 16) & 1u)) >> 16);
}

// async global->LDS, 16B/lane, dest = wave-uniform base + lane*16
__device__ __forceinline__ void gl2lds16(const u16* g, u16* l) {
    __builtin_amdgcn_global_load_lds(
        (const __attribute__((address_space(1))) void*)g,
        (__attribute__((address_space(3))) void*)l, 16, 0, 0);
}

__device__ __forceinline__ s16x8 pack8(float4 a, float4 b) {
    s16x8 w;
    w[0] = (short)f2b(a.x); w[1] = (short)f2b(a.y);
    w[2] = (short)f2b(a.z); w[3] = (short)f2b(a.w);
    w[4] = (short)f2b(b.x); w[5] = (short)f2b(b.y);
    w[6] = (short)f2b(b.z); w[7] = (short)f2b(b.w);
    return w;
}

// ---------------------------------------------------------------------------
// Kernel 1: masked relative-embedding table, 4 variants [4][64][64].
// Sinusoid math bit-faithful to numpy arange fill (verified R3). DO NOT TOUCH.
// ---------------------------------------------------------------------------
__global__ __launch_bounds__(256) void emb4_init_kernel(float* __restrict__ emb4) {
    int idx = blockIdx.x * 256 + threadIdx.x;
    if (idx >= 64 * 64) return;
    int q = idx >> 6, k = idx & 63;

    bool pad = (q >= 49) || (k >= 49);
    float base = 0.f;
    if (!pad) {
        const double step  = 1.0 / 7.0;
        const double delta = __dsub_rn(__dadd_rn(1.0, step), 1.0);
        double xk = __dadd_rn(1.0, __dmul_rn((double)k, delta));
        double xq = __dadd_rn(1.0, __dmul_rn((double)q, delta));
        int xi = (int)__dsub_rn(xk, xq);
        int yi = (k % 7) - (q % 7);
        int r = xi % 13; if (r < 0) r += 13;
        int c = yi % 13; if (c < 0) c += 13;
        const float scl = (float)(-0.7084877209212449);  // -log(10000)/13
        if ((c & 1) == 0) base = sinf((float)r * expf((float)c * scl));
        else              base = cosf((float)r * expf((float)(c - 1) * scl));
    }
    bool rmask = !pad && ((q >= 28) != (k >= 28));
    bool cmask = !pad && ((q % 7 >= 4) != (k % 7 >= 4));
    #pragma unroll
    for (int v = 0; v < 4; ++v) {
        float val = base;
        if (pad || ((v & 1) && rmask) || ((v & 2) && cmask)) val = -INFINITY;
        emb4[v * 4096 + idx] = val;
    }
}

// ---------------------------------------------------------------------------
// Conversion kernels (weights only; activation cvt now fused into QKV GEMM)
// ---------------------------------------------------------------------------
__global__ __launch_bounds__(256) void cvt_transpose_bf16(
    const float* __restrict__ w, u16* __restrict__ wt, int R, int C) {
    int i = blockIdx.x * 256 + threadIdx.x;
    if (i >= R * C) return;
    int r = i / C, c = i % C;
    wt[(size_t)c * R + r] = f2b(w[i]);
}

// QKV transpose with de-interleaving row permutation: GEMM col n' = comp*384+ch
__global__ __launch_bounds__(256) void cvt_transpose_qkv(
    const float* __restrict__ w, u16* __restrict__ wt) {
    int i = blockIdx.x * 256 + threadIdx.x;
    if (i >= 384 * 1152) return;
    int k = i / 1152, col = i % 1152;
    int ch = col / 3, comp = col % 3;
    int np = comp * 384 + ch;
    wt[(size_t)np * 384 + k] = f2b(w[i]);
}

__global__ __launch_bounds__(256) void bias_perm_kernel(
    const float* __restrict__ b, float* __restrict__ bp) {
    int n = blockIdx.x * 256 + threadIdx.x;
    if (n >= 1152) return;
    int comp = n / 384, ch = n % 384;
    bp[n] = b[ch * 3 + comp];
}

// ---------------------------------------------------------------------------
// QKV MFMA GEMM with fused fp32->bf16 A conversion.
// C[M][1152] = bf16(A_f32[M][384]) @ Bt[1152][384]^T + bias, bf16 out.
// 128x128 tile, BK=32, 4 waves (64x64 quadrants). A: reg-staged (4x float4 ->
// cvt -> 2x swizzled ds_write_b128, issue-early/write-late). B: gload_lds w16,
// pre-swizzled source (R8-verified: 0 conflicts). Ping-pong dbuf, counted
// vmcnt ledger: loop-top outstanding {A(t):4, B(t):2}; after issuing t+1 -> 8,
// vmcnt(6) = B(t) drained, t+1 stays in flight across the barrier.
// sched_barrier(0) fences pin VMEM issue order (A-group before B-group).
// Grid: bijective XCD swizzle (m204), R8-verified.
// ---------------------------------------------------------------------------
__global__ __launch_bounds__(256) void mfma_gemm_qkv(
    const float* __restrict__ A, const u16* __restrict__ Bt,
    const float* __restrict__ bias, u16* __restrict__ outb,
    int N, int K)
{
    __shared__ __align__(16) u16 As[2][4096];   // [128][32] swizzled
    __shared__ __align__(16) u16 Bs[2][4096];

    const int tid  = threadIdx.x;
    const int lane = tid & 63;
    const int wid  = tid >> 6;
    const int wr   = wid >> 1, wc = wid & 1;
    const int l15  = lane & 15, l4 = lane >> 4;

    // bijective XCD remap (m204)
    const int gx  = gridDim.x;
    const int nwg = gx * gridDim.y;
    int wg  = blockIdx.y * gx + blockIdx.x;
    int q8  = nwg >> 3, r8 = nwg & 7;
    int xcd = wg & 7, idx = wg >> 3;
    int nid = (xcd < r8 ? xcd * (q8 + 1) : r8 * (q8 + 1) + (xcd - r8) * q8) + idx;
    const int bm = nid / gx, bn = nid % gx;

    // staging geometry
    const int srow  = tid >> 2;                  // 0..63 (block-wide for A)
    const int sk8   = (tid & 3) * 8;             // logical k-offset (fp32 elems)
    const int swz   = (tid & 3) ^ ((srow >> 1) & 3);   // phys 16B slot for A write
    const int bsrow = lane >> 2;                 // B staging (per-wave rows)
    const int bslot = (lane & 3) ^ ((bsrow >> 1) & 3); // pre-swizzled B source

    const float* pAf0 = A + (size_t)(bm * 128 + srow) * K + sk8;
    const float* pAf1 = A + (size_t)(bm * 128 + 64 + srow) * K + sk8;
    const u16* pB0 = Bt + (size_t)(bn * 128 +      wid * 16 + bsrow) * K + bslot * 8;
    const u16* pB1 = Bt + (size_t)(bn * 128 + 64 + wid * 16 + bsrow) * K + bslot * 8;

    f32x4 acc[4][4] = {};
    const int NT = K >> 5;

    // prologue: issue A(0) reg-loads (older) then B(0) gloads
    float4 a00 = *(const float4*)(pAf0);
    float4 a01 = *(const float4*)(pAf0 + 4);
    float4 a10 = *(const float4*)(pAf1);
    float4 a11 = *(const float4*)(pAf1 + 4);
    __builtin_amdgcn_sched_barrier(0);
    gl2lds16(pB0, (u16*)((char*)Bs[0] + wid * 1024));
    gl2lds16(pB1, (u16*)((char*)Bs[0] + 4096 + wid * 1024));
    __builtin_amdgcn_sched_barrier(0);

    for (int t = 0; t < NT; ++t) {
        const int buf = t & 1;
        // A(t) regs ready (compiler waits vmcnt for a00.. use; B(t) in flight)
        *(s16x8*)((char*)As[buf] + srow * 64 + swz * 16)        = pack8(a00, a01);
        *(s16x8*)((char*)As[buf] + (srow + 64) * 64 + swz * 16) = pack8(a10, a11);

        if (t + 1 < NT) {
            const int kt1 = (t + 1) << 5;
            a00 = *(const float4*)(pAf0 + kt1);
            a01 = *(const float4*)(pAf0 + kt1 + 4);
            a10 = *(const float4*)(pAf1 + kt1);
            a11 = *(const float4*)(pAf1 + kt1 + 4);
            __builtin_amdgcn_sched_barrier(0);
            gl2lds16(pB0 + kt1, (u16*)((char*)Bs[buf ^ 1] + wid * 1024));
            gl2lds16(pB1 + kt1, (u16*)((char*)Bs[buf ^ 1] + 4096 + wid * 1024));
            __builtin_amdgcn_sched_barrier(0);
            asm volatile("s_waitcnt vmcnt(6)" ::: "memory");   // B(t) landed
        } else {
            asm volatile("s_waitcnt vmcnt(0)" ::: "memory");
        }
        asm volatile("s_waitcnt lgkmcnt(0)" ::: "memory");      // my A writes done
        __builtin_amdgcn_s_barrier();                           // tile t visible
        __builtin_amdgcn_sched_barrier(0);

        s16x8 af[4], bf[4];
        #pragma unroll
        for (int m = 0; m < 4; ++m) {
            int rm = wr * 64 + m * 16 + l15;
            af[m] = *(const s16x8*)((const char*)As[buf] + rm * 64
                                    + ((l4 ^ ((rm >> 1) & 3)) << 4));
        }
        #pragma unroll
        for (int n = 0; n < 4; ++n) {
            int rn = wc * 64 + n * 16 + l15;
            bf[n] = *(const s16x8*)((const char*)Bs[buf] + rn * 64
                                    + ((l4 ^ ((rn >> 1) & 3)) << 4));
        }
        #pragma unroll
        for (int m = 0; m < 4; ++m)
            #pragma unroll
            for (int n = 0; n < 4; ++n)
                acc[m][n] = __builtin_amdgcn_mfma_f32_16x16x32_bf16(
                    af[m], bf[n], acc[m][n], 0, 0, 0);

        asm volatile("s_waitcnt lgkmcnt(0)" ::: "memory");      // frag reads done
        __builtin_amdgcn_sched_barrier(0);
        __builtin_amdgcn_s_barrier();                           // buf reusable
    }

    const int grow0 = bm * 128 + wr * 64;
    const int gcol0 = bn * 128 + wc * 64;
    #pragma unroll
    for (int m = 0; m < 4; ++m) {
        #pragma unroll
        for (int n = 0; n < 4; ++n) {
            int col = gcol0 + n * 16 + l15;
            float bz = bias[col];
            #pragma unroll
            for (int r = 0; r < 4; ++r) {
                int row = grow0 + m * 16 + l4 * 4 + r;
                outb[(size_t)row * N + col] = f2b(acc[m][n][r] + bz);
            }
        }
    }
}

// ---------------------------------------------------------------------------
// Out-proj MFMA GEMM (R9-verified structure, MODE 1 only): fp32 out + bias.
// ---------------------------------------------------------------------------
__global__ __launch_bounds__(256) void mfma_gemm_out(
    const u16* __restrict__ A, const u16* __restrict__ Bt,
    const float* __restrict__ bias, float* __restrict__ outf,
    int N, int K)
{
    __shared__ __align__(16) u16 As[2][4096];
    __shared__ __align__(16) u16 Bs[2][4096];

    const int tid  = threadIdx.x;
    const int lane = tid & 63;
    const int wid  = tid >> 6;
    const int wr   = wid >> 1, wc = wid & 1;
    const int l15  = lane & 15, l4 = lane >> 4;

    const int gx  = gridDim.x;
    const int nwg = gx * gridDim.y;
    int wg  = blockIdx.y * gx + blockIdx.x;
    int q8  = nwg >> 3, r8 = nwg & 7;
    int xcd = wg & 7, idx = wg >> 3;
    int nid = (xcd < r8 ? xcd * (q8 + 1) : r8 * (q8 + 1) + (xcd - r8) * q8) + idx;
    const int bm = nid / gx, bn = nid % gx;

    const int srow  = lane >> 2;
    const int sslot = (lane & 3) ^ ((srow >> 1) & 3);

    const u16* pA0 = A  + (size_t)(bm * 128 +      wid * 16 + srow) * K + sslot * 8;
    const u16* pA1 = A  + (size_t)(bm * 128 + 64 + wid * 16 + srow) * K + sslot * 8;
    const u16* pB0 = Bt + (size_t)(bn * 128 +      wid * 16 + srow) * K + sslot * 8;
    const u16* pB1 = Bt + (size_t)(bn * 128 + 64 + wid * 16 + srow) * K + sslot * 8;

    f32x4 acc[4][4] = {};
    const int NT = K >> 5;

    {
        gl2lds16(pA0, (u16*)((char*)As[0] + wid * 1024));
        gl2lds16(pA1, (u16*)((char*)As[0] + 4096 + wid * 1024));
        gl2lds16(pB0, (u16*)((char*)Bs[0] + wid * 1024));
        gl2lds16(pB1, (u16*)((char*)Bs[0] + 4096 + wid * 1024));
    }

    for (int t = 0; t < NT; ++t) {
        const int buf = t & 1;
        if (t + 1 < NT) {
            const int kt1 = (t + 1) << 5;
            gl2lds16(pA0 + kt1, (u16*)((char*)As[buf ^ 1] + wid * 1024));
            gl2lds16(pA1 + kt1, (u16*)((char*)As[buf ^ 1] + 4096 + wid * 1024));
            gl2lds16(pB0 + kt1, (u16*)((char*)Bs[buf ^ 1] + wid * 1024));
            gl2lds16(pB1 + kt1, (u16*)((char*)Bs[buf ^ 1] + 4096 + wid * 1024));
            asm volatile("s_waitcnt vmcnt(4)" ::: "memory");
        } else {
            asm volatile("s_waitcnt vmcnt(0)" ::: "memory");
        }
        __builtin_amdgcn_s_barrier();
        __builtin_amdgcn_sched_barrier(0);

        s16x8 af[4], bf[4];
        #pragma unroll
        for (int m = 0; m < 4; ++m) {
            int rm = wr * 64 + m * 16 + l15;
            af[m] = *(const s16x8*)((const char*)As[buf] + rm * 64
                                    + ((l4 ^ ((rm >> 1) & 3)) << 4));
        }
        #pragma unroll
        for (int n = 0; n < 4; ++n) {
            int rn = wc * 64 + n * 16 + l15;
            bf[n] = *(const s16x8*)((const char*)Bs[buf] + rn * 64
                                    + ((l4 ^ ((rn >> 1) & 3)) << 4));
        }
        #pragma unroll
        for (int m = 0; m < 4; ++m)
            #pragma unroll
            for (int n = 0; n < 4; ++n)
                acc[m][n] = __builtin_amdgcn_mfma_f32_16x16x32_bf16(
                    af[m], bf[n], acc[m][n], 0, 0, 0);

        asm volatile("s_waitcnt lgkmcnt(0)" ::: "memory");
        __builtin_amdgcn_sched_barrier(0);
        __builtin_amdgcn_s_barrier();
    }

    const int grow0 = bm * 128 + wr * 64;
    const int gcol0 = bn * 128 + wc * 64;
    #pragma unroll
    for (int m = 0; m < 4; ++m) {
        #pragma unroll
        for (int n = 0; n < 4; ++n) {
            int col = gcol0 + n * 16 + l15;
            float bz = bias[col];
            #pragma unroll
            for (int r = 0; r < 4; ++r) {
                int row = grow0 + m * 16 + l4 * 4 + r;
                outf[(size_t)row * N + col] = acc[m][n][r] + bz;
            }
        }
    }
}

// ---------------------------------------------------------------------------
// Kernel 3: MFMA windowed attention, stageless (verified R7). Unchanged.
// ---------------------------------------------------------------------------
__global__ __launch_bounds__(256) void attn_mfma_kernel(
    const u16* __restrict__ qkv, const float* __restrict__ emb4,
    u16* __restrict__ att)
{
    __shared__ __align__(16) u16 P4[4][64 * 72];   // 36864 B
    __shared__ int rowIn[64];
    __shared__ int rowOut[64];

    const int tid  = threadIdx.x;
    const int lane = tid & 63;
    const int wid  = tid >> 6;
    const int l15  = lane & 15, l4 = lane >> 4;

    const int blk = blockIdx.x;
    const int hg  = blk % 3;
    const int win = (blk / 3) & 63;
    const int b   = blk / 192;
    const int bw  = win & 7, bh = win >> 3;
    const int head = hg * 4 + wid;

    if (tid < 64) {                                 // roll(-4,-4) gather LUT
        int pix = tid;
        int gr = (bh * 7 + pix / 7 + 4) % IMG;
        int gc = (bw * 7 + pix % 7 + 4) % IMG;
        rowIn[pix] = (b * IMG + gr) * IMG + gc;
    } else if (tid < 128) {                         // roll(+3,+3) scatter LUT
        int q = tid - 64;
        int fr = (bh * 7 + q / 7 + 3) % IMG;
        int fc = (bw * 7 + q % 7 + 3) % IMG;
        rowOut[q] = (b * IMG + fr) * IMG + fc;
    }
    __syncthreads();

    s16x8 qf[4], kf[4];
    #pragma unroll
    for (int n = 0; n < 4; ++n) {
        int pix = n * 16 + l15;
        size_t base = (size_t)rowIn[pix] * NQKV + head * 32 + l4 * 8;
        qf[n] = *(const s16x8*)(qkv + base);          // Q
        kf[n] = *(const s16x8*)(qkv + base + 384);    // K
    }

    f32x4 sc[4][4] = {};
    #pragma unroll
    for (int m = 0; m < 4; ++m)
        #pragma unroll
        for (int n = 0; n < 4; ++n)
            sc[m][n] = __builtin_amdgcn_mfma_f32_16x16x32_bf16(
                kf[m], qf[n], sc[m][n], 0, 0, 0);

    const float scale = 0.17677669529663687f;        // 1/sqrt(32)
    const float* ev = emb4 + ((bh == 7 ? 1 : 0) + (bw == 7 ? 2 : 0)) * 4096;
    u16* P = P4[wid];
    u32* P32 = (u32*)P;

    #pragma unroll
    for (int n = 0; n < 4; ++n) {
        const int q = n * 16 + l15;
        float vals[4][4];
        float mx = -INFINITY;
        #pragma unroll
        for (int m = 0; m < 4; ++m) {
            float4 e4 = *(const float4*)(ev + q * 64 + m * 16 + l4 * 4);
            #pragma unroll
            for (int r = 0; r < 4; ++r) {
                float v = sc[m][n][r] * scale + ((const float*)&e4)[r];
                vals[m][r] = v;
                mx = fmaxf(mx, v);
            }
        }
        mx = fmaxf(mx, __shfl_xor(mx, 16));
        mx = fmaxf(mx, __shfl_xor(mx, 32));
        float sum = 0.f;
        #pragma unroll
        for (int m = 0; m < 4; ++m)
            #pragma unroll
            for (int r = 0; r < 4; ++r) {
                float p = __expf(vals[m][r] - mx);
                vals[m][r] = p;
                sum += p;
            }
        sum += __shfl_xor(sum, 16);
        sum += __shfl_xor(sum, 32);
        float inv = 1.f / sum;
        #pragma unroll
        for (int m = 0; m < 4; ++m) {
            u32 w0 = (u32)f2b(vals[m][0] * inv) | ((u32)f2b(vals[m][1] * inv) << 16);
            u32 w1 = (u32)f2b(vals[m][2] * inv) | ((u32)f2b(vals[m][3] * inv) << 16);
            int bidx = q * 36 + m * 8 + l4 * 2;
            P32[bidx]     = w0;
            P32[bidx + 1] = w1;
        }
    }
    // per-wave private LDS RAW: compiler inserts lgkmcnt waits; no barrier.

    f32x4 o[4][2] = {};
    #pragma unroll
    for (int kh = 0; kh < 2; ++kh) {
        s16x8 pf[4];
        #pragma unroll
        for (int mq = 0; mq < 4; ++mq)
            pf[mq] = *(const s16x8*)&P[(mq * 16 + l15) * 72 + kh * 32 + l4 * 8];
        s16x8 vf[2];
        #pragma unroll
        for (int ne = 0; ne < 2; ++ne) {
            #pragma unroll
            for (int j = 0; j < 8; ++j) {
                int pix = kh * 32 + l4 * 8 + j;
                vf[ne][j] = (short)qkv[(size_t)rowIn[pix] * NQKV + 768
                                       + head * 32 + ne * 16 + l15];
            }
        }
        #pragma unroll
        for (int mq = 0; mq < 4; ++mq)
            #pragma unroll
            for (int ne = 0; ne < 2; ++ne)
                o[mq][ne] = __builtin_amdgcn_mfma_f32_16x16x32_bf16(
                    pf[mq], vf[ne], o[mq][ne], 0, 0, 0);
    }

    #pragma unroll
    for (int mq = 0; mq < 4; ++mq) {
        #pragma unroll
        for (int r = 0; r < 4; ++r) {
            int q = mq * 16 + l4 * 4 + r;
            if (q < 49) {
                size_t rowb = (size_t)rowOut[q] * DIM + head * 32;
                #pragma unroll
                for (int ne = 0; ne < 2; ++ne)
                    att[rowb + ne * 16 + l15] = f2b(o[mq][ne][r]);
            }
        }
    }
}

// ---------------------------------------------------------------------------
extern "C" void kernel_launch(void* const* d_in, const int* in_sizes, int n_in,
                              void* d_out, int out_size, void* d_ws, size_t ws_size,
                              hipStream_t stream) {
    const float* x     = (const float*)d_in[0];
    const float* w_qkv = (const float*)d_in[1];
    const float* b_qkv = (const float*)d_in[2];
    const float* w_out = (const float*)d_in[3];
    const float* b_out = (const float*)d_in[4];
    float* out = (float*)d_out;

    char* wsp = (char*)d_ws;
    float* emb4  = (float*)wsp;                                  // 64 KB
    u16*   wqkvt = (u16*)(wsp + 65536);                          // [1152][384]
    u16*   woutt = (u16*)(wsp + 65536 + 884736);                 // [384][384]
    float* bqkvp = (float*)(wsp + 65536 + 884736 + 294912);      // [1152]
    const size_t fixed = 65536 + 884736 + 294912 + 4608;         // 1,249,792 B

    // per-batch chunk bytes: qkv (bf16) + att (bf16); x read in place
    const size_t perb = (size_t)ROWS_PER_B * (NQKV + DIM) * 2;   // 9,633,792
    int nb = 16;
    while (nb > 2 && fixed + (size_t)nb * perb > ws_size) nb >>= 1;

    u16* qkvb = (u16*)(wsp + fixed);
    u16* attb = qkvb + (size_t)nb * ROWS_PER_B * NQKV;

    emb4_init_kernel<<<16, 256, 0, stream>>>(emb4);
    cvt_transpose_qkv<<<(384 * 1152 + 255) / 256, 256, 0, stream>>>(w_qkv, wqkvt);
    cvt_transpose_bf16<<<(384 * 384 + 255) / 256, 256, 0, stream>>>(w_out, woutt, 384, 384);
    bias_perm_kernel<<<5, 256, 0, stream>>>(b_qkv, bqkvp);

    for (int b0 = 0; b0 < 16; b0 += nb) {
        const int rows = nb * ROWS_PER_B;
        const float* xa = x + (size_t)b0 * ROWS_PER_B * DIM;

        mfma_gemm_qkv<<<dim3(NQKV / 128, rows / 128), 256, 0, stream>>>(
            xa, wqkvt, bqkvp, qkvb, NQKV, DIM);

        attn_mfma_kernel<<<nb * 192, 256, 0, stream>>>(qkvb, emb4, attb);

        mfma_gemm_out<<<dim3(DIM / 128, rows / 128), 256, 0, stream>>>(
            attb, woutt, b_out, out + (size_t)b0 * ROWS_PER_B * DIM, DIM, DIM);
    }
}

// Round 11
// 180.937 us; speedup vs baseline: 1.1069x; 1.1069x over previous
//
#include <hip/hip_runtime.h>
#include <math.h>

// Problem constants
#define DIM   384
#define NQKV  1152
#define IMG   56
#define ROWS_PER_B (IMG*IMG)           // 3136 pixels per batch image

typedef unsigned short u16;
typedef unsigned int u32;
typedef __attribute__((ext_vector_type(4))) float f32x4;
typedef __attribute__((ext_vector_type(8))) short s16x8;

__device__ __forceinline__ u16 f2b(float f) {           // fp32 -> bf16 RNE
    unsigned u = __float_as_uint(f);
    return (u16)((u + 0x7fffu + ((u >> 16) & 1u)) >> 16);
}

// async global->LDS, 16B/lane, dest = wave-uniform base + lane*16
__device__ __forceinline__ void gl2lds16(const u16* g, u16* l) {
    __builtin_amdgcn_global_load_lds(
        (const __attribute__((address_space(1))) void*)g,
        (__attribute__((address_space(3))) void*)l, 16, 0, 0);
}

// ---------------------------------------------------------------------------
// Kernel 1: masked relative-embedding table, 4 variants [4][64][64].
// Sinusoid math bit-faithful to numpy arange fill (verified R3). DO NOT TOUCH.
// ---------------------------------------------------------------------------
__global__ __launch_bounds__(256) void emb4_init_kernel(float* __restrict__ emb4) {
    int idx = blockIdx.x * 256 + threadIdx.x;
    if (idx >= 64 * 64) return;
    int q = idx >> 6, k = idx & 63;

    bool pad = (q >= 49) || (k >= 49);
    float base = 0.f;
    if (!pad) {
        const double step  = 1.0 / 7.0;
        const double delta = __dsub_rn(__dadd_rn(1.0, step), 1.0);
        double xk = __dadd_rn(1.0, __dmul_rn((double)k, delta));
        double xq = __dadd_rn(1.0, __dmul_rn((double)q, delta));
        int xi = (int)__dsub_rn(xk, xq);
        int yi = (k % 7) - (q % 7);
        int r = xi % 13; if (r < 0) r += 13;
        int c = yi % 13; if (c < 0) c += 13;
        const float scl = (float)(-0.7084877209212449);  // -log(10000)/13
        if ((c & 1) == 0) base = sinf((float)r * expf((float)c * scl));
        else              base = cosf((float)r * expf((float)(c - 1) * scl));
    }
    bool rmask = !pad && ((q >= 28) != (k >= 28));
    bool cmask = !pad && ((q % 7 >= 4) != (k % 7 >= 4));
    #pragma unroll
    for (int v = 0; v < 4; ++v) {
        float val = base;
        if (pad || ((v & 1) && rmask) || ((v & 2) && cmask)) val = -INFINITY;
        emb4[v * 4096 + idx] = val;
    }
}

// ---------------------------------------------------------------------------
// Conversion kernels
// ---------------------------------------------------------------------------
__global__ __launch_bounds__(256) void cvt_f32_bf16(
    const float* __restrict__ in, u16* __restrict__ out, int n4) {
    int i = blockIdx.x * 256 + threadIdx.x;
    if (i >= n4) return;
    float4 v = ((const float4*)in)[i];
    ushort4 o;
    o.x = f2b(v.x); o.y = f2b(v.y); o.z = f2b(v.z); o.w = f2b(v.w);
    ((ushort4*)out)[i] = o;
}

__global__ __launch_bounds__(256) void cvt_transpose_bf16(
    const float* __restrict__ w, u16* __restrict__ wt, int R, int C) {
    int i = blockIdx.x * 256 + threadIdx.x;
    if (i >= R * C) return;
    int r = i / C, c = i % C;
    wt[(size_t)c * R + r] = f2b(w[i]);
}

// QKV transpose with de-interleaving row permutation: GEMM col n' = comp*384+ch
__global__ __launch_bounds__(256) void cvt_transpose_qkv(
    const float* __restrict__ w, u16* __restrict__ wt) {
    int i = blockIdx.x * 256 + threadIdx.x;
    if (i >= 384 * 1152) return;
    int k = i / 1152, col = i % 1152;
    int ch = col / 3, comp = col % 3;
    int np = comp * 384 + ch;
    wt[(size_t)np * 384 + k] = f2b(w[i]);
}

__global__ __launch_bounds__(256) void bias_perm_kernel(
    const float* __restrict__ b, float* __restrict__ bp) {
    int n = blockIdx.x * 256 + threadIdx.x;
    if (n >= 1152) return;
    int comp = n / 384, ch = n % 384;
    bp[n] = b[ch * 3 + comp];
}

// ---------------------------------------------------------------------------
// MFMA bf16 GEMM: C[M][N] = A[M][K] @ Bt[N][K]^T + bias.
// 128x128 tile, BK=32, 4 waves (64x64 quadrants, 4x4 frags of 16x16x32).
// Staging: global_load_lds width=16, rule-21 both-sides swizzle (R8-verified:
// 0 conflicts). NEW: 3-buffer LDS ring, 2-deep prefetch, counted vmcnt —
// per K-step: issue STAGE(t+2), wait vmcnt(8) (exactly tile t's 4 loads
// drained; t+1/t+2's 8 stay in flight ACROSS the barrier), s_barrier,
// ds_read+MFMA(buf t%3), lgkmcnt(0)+s_barrier (reads done before the buffer
// is re-staged at iter t+1). Epilogue: vmcnt(4) then vmcnt(0).
// Grid: bijective XCD swizzle (m204), R8-verified (FETCH 167->32 MB).
// MODE 0: bf16 out (QKV). MODE 1: fp32 out (final projection).
// ---------------------------------------------------------------------------
template <int MODE>
__global__ __launch_bounds__(256) void mfma_gemm(
    const u16* __restrict__ A, const u16* __restrict__ Bt,
    const float* __restrict__ bias,
    u16* __restrict__ outb, float* __restrict__ outf,
    int N, int K)
{
    __shared__ __align__(16) u16 As[3][4096];   // [128][32] swizzled, ring x3
    __shared__ __align__(16) u16 Bs[3][4096];

    const int tid  = threadIdx.x;
    const int lane = tid & 63;
    const int wid  = tid >> 6;
    const int wr   = wid >> 1, wc = wid & 1;
    const int l15  = lane & 15, l4 = lane >> 4;

    // bijective XCD remap (m204): contiguous chunk of blocks per XCD
    const int gx  = gridDim.x;
    const int nwg = gx * gridDim.y;
    int wg  = blockIdx.y * gx + blockIdx.x;
    int q8  = nwg >> 3, r8 = nwg & 7;
    int xcd = wg & 7, idx = wg >> 3;
    int nid = (xcd < r8 ? xcd * (q8 + 1) : r8 * (q8 + 1) + (xcd - r8) * q8) + idx;
    const int bm = nid / gx, bn = nid % gx;

    // staging geometry: phys slot16 = lane&3; logical slot = (lane&3)^((srow>>1)&3)
    const int srow  = lane >> 2;
    const int sslot = (lane & 3) ^ ((srow >> 1) & 3);

    const u16* pA0 = A  + (size_t)(bm * 128 +      wid * 16 + srow) * K + sslot * 8;
    const u16* pA1 = A  + (size_t)(bm * 128 + 64 + wid * 16 + srow) * K + sslot * 8;
    const u16* pB0 = Bt + (size_t)(bn * 128 +      wid * 16 + srow) * K + sslot * 8;
    const u16* pB1 = Bt + (size_t)(bn * 128 + 64 + wid * 16 + srow) * K + sslot * 8;

    f32x4 acc[4][4] = {};
    const int NT = K >> 5;

    #define STAGE(t)                                                          \
        do {                                                                  \
            const int _kt = (t) << 5;                                         \
            const int _rb = (t) % 3;                                          \
            gl2lds16(pA0 + _kt, (u16*)((char*)As[_rb] + wid * 1024));         \
            gl2lds16(pA1 + _kt, (u16*)((char*)As[_rb] + 4096 + wid * 1024));  \
            gl2lds16(pB0 + _kt, (u16*)((char*)Bs[_rb] + wid * 1024));         \
            gl2lds16(pB1 + _kt, (u16*)((char*)Bs[_rb] + 4096 + wid * 1024));  \
        } while (0)

    STAGE(0);
    STAGE(1);

    for (int t = 0; t < NT; ++t) {
        if (t + 2 < NT) {
            STAGE(t + 2);
            asm volatile("s_waitcnt vmcnt(8)" ::: "memory");   // tile t landed
        } else if (t + 2 == NT) {
            asm volatile("s_waitcnt vmcnt(4)" ::: "memory");
        } else {
            asm volatile("s_waitcnt vmcnt(0)" ::: "memory");
        }
        __builtin_amdgcn_s_barrier();          // tile t visible to all waves
        __builtin_amdgcn_sched_barrier(0);

        const int buf = t % 3;
        s16x8 af[4], bf[4];
        #pragma unroll
        for (int m = 0; m < 4; ++m) {
            int rm = wr * 64 + m * 16 + l15;
            af[m] = *(const s16x8*)((const char*)As[buf] + rm * 64
                                    + ((l4 ^ ((rm >> 1) & 3)) << 4));
        }
        #pragma unroll
        for (int n = 0; n < 4; ++n) {
            int rn = wc * 64 + n * 16 + l15;
            bf[n] = *(const s16x8*)((const char*)Bs[buf] + rn * 64
                                    + ((l4 ^ ((rn >> 1) & 3)) << 4));
        }
        #pragma unroll
        for (int m = 0; m < 4; ++m)
            #pragma unroll
            for (int n = 0; n < 4; ++n)
                acc[m][n] = __builtin_amdgcn_mfma_f32_16x16x32_bf16(
                    af[m], bf[n], acc[m][n], 0, 0, 0);

        // reads of buf complete before iter t+1 re-stages it
        asm volatile("s_waitcnt lgkmcnt(0)" ::: "memory");
        __builtin_amdgcn_sched_barrier(0);
        __builtin_amdgcn_s_barrier();
    }
    #undef STAGE

    const int grow0 = bm * 128 + wr * 64;
    const int gcol0 = bn * 128 + wc * 64;
    #pragma unroll
    for (int m = 0; m < 4; ++m) {
        #pragma unroll
        for (int n = 0; n < 4; ++n) {
            int col = gcol0 + n * 16 + l15;
            float bz = bias[col];
            #pragma unroll
            for (int r = 0; r < 4; ++r) {
                int row = grow0 + m * 16 + l4 * 4 + r;
                float v = acc[m][n][r] + bz;
                if constexpr (MODE == 0)
                    outb[(size_t)row * N + col] = f2b(v);
                else
                    outf[(size_t)row * N + col] = v;
            }
        }
    }
}

// ---------------------------------------------------------------------------
// Kernel 3: MFMA windowed attention, stageless (verified R7). Unchanged.
// ---------------------------------------------------------------------------
__global__ __launch_bounds__(256) void attn_mfma_kernel(
    const u16* __restrict__ qkv, const float* __restrict__ emb4,
    u16* __restrict__ att)
{
    __shared__ __align__(16) u16 P4[4][64 * 72];   // 36864 B
    __shared__ int rowIn[64];
    __shared__ int rowOut[64];

    const int tid  = threadIdx.x;
    const int lane = tid & 63;
    const int wid  = tid >> 6;
    const int l15  = lane & 15, l4 = lane >> 4;

    const int blk = blockIdx.x;
    const int hg  = blk % 3;
    const int win = (blk / 3) & 63;
    const int b   = blk / 192;
    const int bw  = win & 7, bh = win >> 3;
    const int head = hg * 4 + wid;

    if (tid < 64) {                                 // roll(-4,-4) gather LUT
        int pix = tid;
        int gr = (bh * 7 + pix / 7 + 4) % IMG;
        int gc = (bw * 7 + pix % 7 + 4) % IMG;
        rowIn[pix] = (b * IMG + gr) * IMG + gc;
    } else if (tid < 128) {                         // roll(+3,+3) scatter LUT
        int q = tid - 64;
        int fr = (bh * 7 + q / 7 + 3) % IMG;
        int fc = (bw * 7 + q % 7 + 3) % IMG;
        rowOut[q] = (b * IMG + fr) * IMG + fc;
    }
    __syncthreads();

    s16x8 qf[4], kf[4];
    #pragma unroll
    for (int n = 0; n < 4; ++n) {
        int pix = n * 16 + l15;
        size_t base = (size_t)rowIn[pix] * NQKV + head * 32 + l4 * 8;
        qf[n] = *(const s16x8*)(qkv + base);          // Q
        kf[n] = *(const s16x8*)(qkv + base + 384);    // K
    }

    f32x4 sc[4][4] = {};
    #pragma unroll
    for (int m = 0; m < 4; ++m)
        #pragma unroll
        for (int n = 0; n < 4; ++n)
            sc[m][n] = __builtin_amdgcn_mfma_f32_16x16x32_bf16(
                kf[m], qf[n], sc[m][n], 0, 0, 0);

    const float scale = 0.17677669529663687f;        // 1/sqrt(32)
    const float* ev = emb4 + ((bh == 7 ? 1 : 0) + (bw == 7 ? 2 : 0)) * 4096;
    u16* P = P4[wid];
    u32* P32 = (u32*)P;

    #pragma unroll
    for (int n = 0; n < 4; ++n) {
        const int q = n * 16 + l15;
        float vals[4][4];
        float mx = -INFINITY;
        #pragma unroll
        for (int m = 0; m < 4; ++m) {
            float4 e4 = *(const float4*)(ev + q * 64 + m * 16 + l4 * 4);
            #pragma unroll
            for (int r = 0; r < 4; ++r) {
                float v = sc[m][n][r] * scale + ((const float*)&e4)[r];
                vals[m][r] = v;
                mx = fmaxf(mx, v);
            }
        }
        mx = fmaxf(mx, __shfl_xor(mx, 16));
        mx = fmaxf(mx, __shfl_xor(mx, 32));
        float sum = 0.f;
        #pragma unroll
        for (int m = 0; m < 4; ++m)
            #pragma unroll
            for (int r = 0; r < 4; ++r) {
                float p = __expf(vals[m][r] - mx);
                vals[m][r] = p;
                sum += p;
            }
        sum += __shfl_xor(sum, 16);
        sum += __shfl_xor(sum, 32);
        float inv = 1.f / sum;
        #pragma unroll
        for (int m = 0; m < 4; ++m) {
            u32 w0 = (u32)f2b(vals[m][0] * inv) | ((u32)f2b(vals[m][1] * inv) << 16);
            u32 w1 = (u32)f2b(vals[m][2] * inv) | ((u32)f2b(vals[m][3] * inv) << 16);
            int bidx = q * 36 + m * 8 + l4 * 2;
            P32[bidx]     = w0;
            P32[bidx + 1] = w1;
        }
    }
    // per-wave private LDS RAW: compiler inserts lgkmcnt waits; no barrier.

    f32x4 o[4][2] = {};
    #pragma unroll
    for (int kh = 0; kh < 2; ++kh) {
        s16x8 pf[4];
        #pragma unroll
        for (int mq = 0; mq < 4; ++mq)
            pf[mq] = *(const s16x8*)&P[(mq * 16 + l15) * 72 + kh * 32 + l4 * 8];
        s16x8 vf[2];
        #pragma unroll
        for (int ne = 0; ne < 2; ++ne) {
            #pragma unroll
            for (int j = 0; j < 8; ++j) {
                int pix = kh * 32 + l4 * 8 + j;
                vf[ne][j] = (short)qkv[(size_t)rowIn[pix] * NQKV + 768
                                       + head * 32 + ne * 16 + l15];
            }
        }
        #pragma unroll
        for (int mq = 0; mq < 4; ++mq)
            #pragma unroll
            for (int ne = 0; ne < 2; ++ne)
                o[mq][ne] = __builtin_amdgcn_mfma_f32_16x16x32_bf16(
                    pf[mq], vf[ne], o[mq][ne], 0, 0, 0);
    }

    #pragma unroll
    for (int mq = 0; mq < 4; ++mq) {
        #pragma unroll
        for (int r = 0; r < 4; ++r) {
            int q = mq * 16 + l4 * 4 + r;
            if (q < 49) {
                size_t rowb = (size_t)rowOut[q] * DIM + head * 32;
                #pragma unroll
                for (int ne = 0; ne < 2; ++ne)
                    att[rowb + ne * 16 + l15] = f2b(o[mq][ne][r]);
            }
        }
    }
}

// ---------------------------------------------------------------------------
extern "C" void kernel_launch(void* const* d_in, const int* in_sizes, int n_in,
                              void* d_out, int out_size, void* d_ws, size_t ws_size,
                              hipStream_t stream) {
    const float* x     = (const float*)d_in[0];
    const float* w_qkv = (const float*)d_in[1];
    const float* b_qkv = (const float*)d_in[2];
    const float* w_out = (const float*)d_in[3];
    const float* b_out = (const float*)d_in[4];
    float* out = (float*)d_out;

    char* wsp = (char*)d_ws;
    float* emb4  = (float*)wsp;                                  // 64 KB
    u16*   wqkvt = (u16*)(wsp + 65536);                          // [1152][384]
    u16*   woutt = (u16*)(wsp + 65536 + 884736);                 // [384][384]
    float* bqkvp = (float*)(wsp + 65536 + 884736 + 294912);      // [1152]
    const size_t fixed = 65536 + 884736 + 294912 + 4608;         // 1,249,792 B

    // per-batch chunk bytes: xb + qkv + att, all bf16
    const size_t perb = (size_t)ROWS_PER_B * (DIM + NQKV + DIM) * 2; // 12,042,240
    int nb = 16;
    while (nb > 2 && fixed + (size_t)nb * perb > ws_size) nb >>= 1;

    u16* xb   = (u16*)(wsp + fixed);
    u16* qkvb = xb   + (size_t)nb * ROWS_PER_B * DIM;
    u16* attb = qkvb + (size_t)nb * ROWS_PER_B * NQKV;

    emb4_init_kernel<<<16, 256, 0, stream>>>(emb4);
    cvt_transpose_qkv<<<(384 * 1152 + 255) / 256, 256, 0, stream>>>(w_qkv, wqkvt);
    cvt_transpose_bf16<<<(384 * 384 + 255) / 256, 256, 0, stream>>>(w_out, woutt, 384, 384);
    bias_perm_kernel<<<5, 256, 0, stream>>>(b_qkv, bqkvp);

    for (int b0 = 0; b0 < 16; b0 += nb) {
        const int rows = nb * ROWS_PER_B;
        const float* xa = x + (size_t)b0 * ROWS_PER_B * DIM;

        cvt_f32_bf16<<<(rows * DIM / 4 + 255) / 256, 256, 0, stream>>>(
            xa, xb, rows * DIM / 4);

        mfma_gemm<0><<<dim3(NQKV / 128, rows / 128), 256, 0, stream>>>(
            xb, wqkvt, bqkvp, qkvb, nullptr, NQKV, DIM);

        attn_mfma_kernel<<<nb * 192, 256, 0, stream>>>(qkvb, emb4, attb);

        mfma_gemm<1><<<dim3(DIM / 128, rows / 128), 256, 0, stream>>>(
            attb, woutt, b_out, nullptr, out + (size_t)b0 * ROWS_PER_B * DIM, DIM, DIM);
    }
}